// Round 3
// baseline (484.421 us; speedup 1.0000x reference)
//
#include <hip/hip_runtime.h>

// Winograd F(2x2x2, 3x3x3) conv: N=4, Ci=Co=128, D=H=W=32, T=16 tiles/dim.
// K1: weight transform into MFMA-fragment-ordered U2.
// K2: input transform -> V[abc][t][ci] bf16. Spill-free streamed transform:
//     fp32 slab + small Tb transpose buffer in separate LDS; each block owns
//     64 ci (two 32-ci slab passes) so V-row 128B lines are written whole.
// K3: 64 batched GEMMs with fused inverse transform; counted-vmcnt pipeline
//     (depth 2), V staged via global_load_lds ring, U prefetched to regs.

typedef short short8 __attribute__((ext_vector_type(8)));
typedef float f32x4 __attribute__((ext_vector_type(4)));

typedef __attribute__((address_space(1))) const void* gas_cvp;
typedef __attribute__((address_space(3))) void* las_vp;

__device__ __forceinline__ unsigned short f2bf(float f) {
  unsigned u = __float_as_uint(f);
  u += 0x7FFFu + ((u >> 16) & 1u);
  return (unsigned short)(u >> 16);
}

// ---------------- K1: weight transform ----------------
// U2 element for (abc, o, ci) lives at
//   abc*16384 + ((g*4 + ks)*64 + hi*16 + lo)*8 + j
// with g=o>>4, lo=o&15, ks=ci>>5, hi=(ci>>3)&3, j=ci&7 -- so a wave's A-frag
// load (lane = hi*16+lo, 16B x 4ks) is fully coalesced (1KB/instr).
__global__ void wt_kernel(const float* __restrict__ w, unsigned short* __restrict__ U) {
  int tid = blockIdx.x * 256 + threadIdx.x;  // 16384 threads
  int ci = tid & 127, o = tid >> 7;
  int g = o >> 4, lo = o & 15, ks = ci >> 5, hi = (ci >> 3) & 3, jj = ci & 7;
  int base2 = ((g * 4 + ks) * 64 + hi * 16 + lo) * 8 + jj;
  const float* wp = w + (size_t)(o * 128 + ci) * 27;
  float in[27];
#pragma unroll
  for (int j = 0; j < 27; ++j) in[j] = wp[j];
  float s1[4][9];
#pragma unroll
  for (int ef = 0; ef < 9; ++ef) {
    float x0 = in[ef], x1 = in[9 + ef], x2 = in[18 + ef];
    s1[0][ef] = x0;
    s1[1][ef] = 0.5f * (x0 + x1 + x2);
    s1[2][ef] = 0.5f * (x0 - x1 + x2);
    s1[3][ef] = x2;
  }
  float s2[4][4][3];
#pragma unroll
  for (int a = 0; a < 4; ++a)
#pragma unroll
    for (int f = 0; f < 3; ++f) {
      float x0 = s1[a][f], x1 = s1[a][3 + f], x2 = s1[a][6 + f];
      s2[a][0][f] = x0;
      s2[a][1][f] = 0.5f * (x0 + x1 + x2);
      s2[a][2][f] = 0.5f * (x0 - x1 + x2);
      s2[a][3][f] = x2;
    }
#pragma unroll
  for (int a = 0; a < 4; ++a)
#pragma unroll
    for (int b = 0; b < 4; ++b) {
      float x0 = s2[a][b][0], x1 = s2[a][b][1], x2 = s2[a][b][2];
      size_t ab = (size_t)(a * 16 + b * 4) * 16384 + base2;
      U[ab + 0 * 16384] = f2bf(x0);
      U[ab + 1 * 16384] = f2bf(0.5f * (x0 + x1 + x2));
      U[ab + 2 * 16384] = f2bf(0.5f * (x0 - x1 + x2));
      U[ab + 3 * 16384] = f2bf(x2);
    }
}

// ---------------- K2: input transform ----------------
// Block: 512 thr = (32 ci) x (16 tiles: 2 th x 8 tw); owns 64 ci via 2 passes.
// Per pass: slab[32ci][4d][6h][18w] fp32 -> per-thread streamed Bt^3:
// s1 (fd-transform, 64 regs) kept; per (a, b-pair): 8 outputs -> Tb[8][16][32]
// bf16 -> coalesced 16B flush to V. No value lives across a barrier -> no
// spill. Bt rows: r0=x0-x2, r1=x1+x2, r2=x2-x1, r3=x1-x3.
__global__ __launch_bounds__(512, 2) void vt_kernel(const float* __restrict__ x,
                                                    unsigned short* __restrict__ V, int n_base,
                                                    int nt_slice) {
  __shared__ __align__(16) float slab[32 * 433];          // 55424 B
  __shared__ __align__(16) unsigned short Tb[8][16][32];  // 8192 B

  int b = blockIdx.x;
  int cib2 = b & 1;  // 64-ci group
  int twb = (b >> 1) & 1;
  int thb = (b >> 2) & 7;
  int td = (b >> 5) & 15;
  int n_l = b >> 9;
  int n = n_base + n_l;
  int d0 = td * 2 - 1, h0 = thb * 4 - 1, w0 = twb * 16 - 1;
  int tg_base = n_l * 4096 + td * 256 + (thb * 2) * 16 + twb * 8;

  int ci_l = threadIdx.x & 31, tl = threadIdx.x >> 5;
  int tw = tl & 7, thl = tl >> 3;

#pragma unroll 1
  for (int pass = 0; pass < 2; ++pass) {
    int CI0 = cib2 * 64 + pass * 32;
    for (int i = threadIdx.x; i < 32 * 432; i += 512) {
      int ci = i / 432, r = i - ci * 432;
      int dd = r / 108, r2 = r - dd * 108;
      int hh = r2 / 18, ww = r2 - hh * 18;
      int dg = d0 + dd, hg = h0 + hh, wg = w0 + ww;
      float v = 0.0f;
      if ((unsigned)dg < 32u && (unsigned)hg < 32u && (unsigned)wg < 32u)
        v = x[((size_t)((n * 128 + CI0 + ci) * 32 + dg) * 32 + hg) * 32 + wg];
      slab[ci * 433 + dd * 108 + hh * 18 + ww] = v;
    }
    __syncthreads();

    const float* sp = slab + ci_l * 433 + (2 * thl) * 18 + 2 * tw;
    float s1[4][16];  // [fd-row][fh*4+fw]
#pragma unroll
    for (int fh = 0; fh < 4; ++fh)
#pragma unroll
      for (int fw = 0; fw < 4; ++fw) {
        float x0 = sp[0 * 108 + fh * 18 + fw];
        float x1 = sp[1 * 108 + fh * 18 + fw];
        float x2 = sp[2 * 108 + fh * 18 + fw];
        float x3 = sp[3 * 108 + fh * 18 + fw];
        s1[0][fh * 4 + fw] = x0 - x2;
        s1[1][fh * 4 + fw] = x1 + x2;
        s1[2][fh * 4 + fw] = x2 - x1;
        s1[3][fh * 4 + fw] = x1 - x3;
      }

#pragma unroll
    for (int a = 0; a < 4; ++a) {
      float s2[4][4];  // [b-row][fw]
#pragma unroll
      for (int fw = 0; fw < 4; ++fw) {
        float t0 = s1[a][0 + fw], t1 = s1[a][4 + fw], t2 = s1[a][8 + fw], t3 = s1[a][12 + fw];
        s2[0][fw] = t0 - t2;
        s2[1][fw] = t1 + t2;
        s2[2][fw] = t2 - t1;
        s2[3][fw] = t1 - t3;
      }
#pragma unroll
      for (int half = 0; half < 2; ++half) {
#pragma unroll
        for (int bi = 0; bi < 2; ++bi) {
          int bb = half * 2 + bi;
          float x0 = s2[bb][0], x1 = s2[bb][1], x2 = s2[bb][2], x3 = s2[bb][3];
          int bcl = bi * 4;
          Tb[bcl + 0][tl][ci_l] = f2bf(x0 - x2);
          Tb[bcl + 1][tl][ci_l] = f2bf(x1 + x2);
          Tb[bcl + 2][tl][ci_l] = f2bf(x2 - x1);
          Tb[bcl + 3][tl][ci_l] = f2bf(x1 - x3);
        }
        __syncthreads();
        {
          int i = threadIdx.x;
          int bcl = i >> 6, r = i & 63, t = r >> 2, c8 = (r & 3) * 8;
          uint4 val = *(const uint4*)&Tb[bcl][t][c8];
          int abc = a * 16 + half * 8 + bcl;
          int tg = tg_base + (t >> 3) * 16 + (t & 7);
          *(uint4*)(V + ((size_t)abc * nt_slice + tg) * 128 + CI0 + c8) = val;
        }
        __syncthreads();
      }
    }
  }
}

// ---------------- K3: batched GEMM + fused inverse transform ----------------
// Grid: img x 4 o-groups(32o) x 128 t-blocks(32t). Block 128 thr = 2 waves,
// each wave 16o x 32t. V staged in 4-deep LDS ring (8KB tiles) via
// global_load_lds (linear dest, inverse-swizzled source); U prefetched into
// rotating registers at the same depth so the per-wave vmcnt stream stays
// uniform: per iter 4 V-lds + 4 U loads -> steady-state s_waitcnt vmcnt(12)
// + raw s_barrier (never drain to 0 in the loop).
__global__ __launch_bounds__(128, 3) void wg_gemm(const unsigned short* __restrict__ U,
                                                  const unsigned short* __restrict__ V,
                                                  float* __restrict__ y, int n_base,
                                                  int nt_slice) {
  __shared__ __align__(16) unsigned short vbuf[4][32 * 128];  // 4 x 8 KB
  const int tid = threadIdx.x;
  const int lane = tid & 63;
  const int wid = tid >> 6;  // 0..1
  const int b = blockIdx.x;
  const int img = b >> 9;
  const int og = (b >> 7) & 3;
  const int tblk = b & 127;
  const int tb = img * 4096 + tblk * 32;  // slice-local tile base
  const int g = og * 2 + wid;             // o-16-group
  const int lo = lane & 15;
  const int hi = lane >> 4;

  const unsigned short* Ug = U + (size_t)g * 2048 + (size_t)lane * 8;

  const f32x4 zf = {0.f, 0.f, 0.f, 0.f};
  f32x4 Y[2][2][2][2];  // [f][k][l][m]
#pragma unroll
  for (int f = 0; f < 2; ++f)
#pragma unroll
    for (int k = 0; k < 2; ++k)
#pragma unroll
      for (int l = 0; l < 2; ++l)
#pragma unroll
        for (int m = 0; m < 2; ++m) Y[f][k][l][m] = zf;
  f32x4 P0[2], P1[2];
  short8 ua[2][4];

  auto stageV = [&](int i) {
    int a = i & 3, bc = i >> 2;
    int abc = a * 16 + bc;
    const char* src = (const char*)(V + ((size_t)abc * nt_slice + tb) * 128);
    char* dstb = (char*)&vbuf[i & 3][0];
#pragma unroll
    for (int it = 0; it < 4; ++it) {
      int L = (tid + it * 128) * 16;
      int t = L >> 8, bo = L & 255;
      int sb = bo ^ ((t & 7) << 4);  // inverse-swizzled global source
      __builtin_amdgcn_global_load_lds((gas_cvp)(src + t * 256 + sb), (las_vp)(dstb + L), 16, 0,
                                       0);
    }
  };
  auto loadU = [&](int i, short8* dst) {
    int a = i & 3, bc = i >> 2;
    int abc = a * 16 + bc;
    const unsigned short* up = Ug + (size_t)abc * 16384;
#pragma unroll
    for (int ks = 0; ks < 4; ++ks) dst[ks] = *(const short8*)(up + ks * 512);
  };

  // prologue: 2 tiles in flight
  stageV(0);
  loadU(0, ua[0]);
  stageV(1);
  loadU(1, ua[1]);

  for (int j4 = 0; j4 < 64; j4 += 4) {
    int bc = j4 >> 2;
#pragma unroll
    for (int p = 0; p < 4; ++p) {
      int i = j4 + p;
      if (i < 62) stageV(i + 2);
      if (i < 62)
        asm volatile("s_waitcnt vmcnt(12)" ::: "memory");
      else if (i == 62)
        asm volatile("s_waitcnt vmcnt(8)" ::: "memory");
      else
        asm volatile("s_waitcnt vmcnt(0)" ::: "memory");
      __builtin_amdgcn_s_barrier();
      const char* vb = (const char*)&vbuf[p][0];  // i & 3 == p
      f32x4 M[2];
#pragma unroll
      for (int ks = 0; ks < 4; ++ks) {
#pragma unroll
        for (int f = 0; f < 2; ++f) {
          int t = f * 16 + lo;
          int boff = (t * 256 + ks * 64 + hi * 16) ^ ((t & 7) << 4);
          short8 Bf = *(const short8*)(vb + boff);
          M[f] = __builtin_amdgcn_mfma_f32_16x16x32_bf16(ua[p & 1][ks], Bf,
                                                         (ks == 0) ? zf : M[f], 0, 0, 0);
        }
      }
      // At rows: [1,1,1,0], [0,1,-1,-1]; a == p
#pragma unroll
      for (int f = 0; f < 2; ++f) {
        if (p == 0) {
          P0[f] = M[f];
          P1[f] = zf;
        } else if (p == 1) {
          P0[f] += M[f];
          P1[f] = M[f];
        } else if (p == 2) {
          P0[f] += M[f];
          P1[f] -= M[f];
        } else {
          P1[f] -= M[f];
        }
      }
      if (i < 62) loadU(i + 2, ua[p & 1]);
    }
    int bq = bc >> 2, cq = bc & 3;
    float cl0 = (bq == 3) ? 0.f : 1.f;
    float cl1 = (bq == 0) ? 0.f : ((bq == 1) ? 1.f : -1.f);
    float cm0 = (cq == 3) ? 0.f : 1.f;
    float cm1 = (cq == 0) ? 0.f : ((cq == 1) ? 1.f : -1.f);
    float c00 = cl0 * cm0, c01 = cl0 * cm1, c10 = cl1 * cm0, c11 = cl1 * cm1;
#pragma unroll
    for (int f = 0; f < 2; ++f) {
      Y[f][0][0][0] += c00 * P0[f];
      Y[f][0][0][1] += c01 * P0[f];
      Y[f][0][1][0] += c10 * P0[f];
      Y[f][0][1][1] += c11 * P0[f];
      Y[f][1][0][0] += c00 * P1[f];
      Y[f][1][0][1] += c01 * P1[f];
      Y[f][1][1][0] += c10 * P1[f];
      Y[f][1][1][1] += c11 * P1[f];
    }
  }

  // write out: o = g*16 + hi*4 + q; t = tb + f*16 + lo
#pragma unroll
  for (int f = 0; f < 2; ++f) {
    int tg = tb + f * 16 + lo;
    int n = n_base + (tg >> 12);
    int rem = tg & 4095;
    int td = rem >> 8, th = (rem >> 4) & 15, tw = rem & 15;
#pragma unroll
    for (int q = 0; q < 4; ++q) {
      int o = g * 16 + hi * 4 + q;
      float* pb = y + (size_t)(n * 128 + o) * 32768 + 2 * tw;
#pragma unroll
      for (int k = 0; k < 2; ++k)
#pragma unroll
        for (int l = 0; l < 2; ++l) {
          float* p = pb + (2 * td + k) * 1024 + (2 * th + l) * 32;
          *(float2*)p = make_float2(Y[f][k][l][0][q], Y[f][k][l][1][q]);
        }
    }
  }
}

extern "C" void kernel_launch(void* const* d_in, const int* in_sizes, int n_in, void* d_out,
                              int out_size, void* d_ws, size_t ws_size, hipStream_t stream) {
  const float* x = (const float*)d_in[0];
  const float* w = (const float*)d_in[1];
  float* y = (float*)d_out;
  char* ws = (char*)d_ws;
  unsigned short* U = (unsigned short*)ws;
  unsigned short* V = (unsigned short*)(ws + (4ull << 20));
  const size_t per_img = 64ull * 4096 * 128 * 2;  // 64 MiB of V per image
  int n_s = 1;
  if (ws_size >= (4ull << 20) + 4 * per_img)
    n_s = 4;
  else if (ws_size >= (4ull << 20) + 2 * per_img)
    n_s = 2;

  wt_kernel<<<64, 256, 0, stream>>>(w, U);
  for (int nb = 0; nb < 4; nb += n_s) {
    int nt_slice = 4096 * n_s;
    vt_kernel<<<dim3(512 * n_s), 512, 0, stream>>>(x, V, nb, nt_slice);
    wg_gemm<<<dim3(512 * n_s), 128, 0, stream>>>(U, V, y, nb, nt_slice);
  }
}

// Round 4
// 472.049 us; speedup vs baseline: 1.0262x; 1.0262x over previous
//
#include <hip/hip_runtime.h>

// Winograd F(2x2x2, 3x3x3) conv: N=4, Ci=Co=128, D=H=W=32, T=16 tiles/dim.
// K1: weight transform into MFMA-fragment-ordered U2.
// K2: input transform, lane=ci design: fp32 slab [64ci][600 spatial] (stride
//     601, bank-conflict-free), each wave transforms tiles with lane=ci and
//     stores V rows as full 128B lines (64 lanes x 2B). One barrier, no LDS
//     transpose, no write amplification.
// K3: 64 batched GEMMs with fused inverse transform; counted-vmcnt pipeline
//     (depth 2), V staged via global_load_lds ring, U prefetched to regs.

typedef short short8 __attribute__((ext_vector_type(8)));
typedef float f32x4 __attribute__((ext_vector_type(4)));

typedef __attribute__((address_space(1))) const void* gas_cvp;
typedef __attribute__((address_space(3))) void* las_vp;

__device__ __forceinline__ unsigned short f2bf(float f) {
  unsigned u = __float_as_uint(f);
  u += 0x7FFFu + ((u >> 16) & 1u);
  return (unsigned short)(u >> 16);
}

// ---------------- K1: weight transform ----------------
// U2 element for (abc, o, ci) lives at
//   abc*16384 + ((g*4 + ks)*64 + hi*16 + lo)*8 + j
// with g=o>>4, lo=o&15, ks=ci>>5, hi=(ci>>3)&3, j=ci&7 -- so a wave's A-frag
// load (lane = hi*16+lo, 16B x 4ks) is fully coalesced (1KB/instr).
__global__ void wt_kernel(const float* __restrict__ w, unsigned short* __restrict__ U) {
  int tid = blockIdx.x * 256 + threadIdx.x;  // 16384 threads
  int ci = tid & 127, o = tid >> 7;
  int g = o >> 4, lo = o & 15, ks = ci >> 5, hi = (ci >> 3) & 3, jj = ci & 7;
  int base2 = ((g * 4 + ks) * 64 + hi * 16 + lo) * 8 + jj;
  const float* wp = w + (size_t)(o * 128 + ci) * 27;
  float in[27];
#pragma unroll
  for (int j = 0; j < 27; ++j) in[j] = wp[j];
  float s1[4][9];
#pragma unroll
  for (int ef = 0; ef < 9; ++ef) {
    float x0 = in[ef], x1 = in[9 + ef], x2 = in[18 + ef];
    s1[0][ef] = x0;
    s1[1][ef] = 0.5f * (x0 + x1 + x2);
    s1[2][ef] = 0.5f * (x0 - x1 + x2);
    s1[3][ef] = x2;
  }
  float s2[4][4][3];
#pragma unroll
  for (int a = 0; a < 4; ++a)
#pragma unroll
    for (int f = 0; f < 3; ++f) {
      float x0 = s1[a][f], x1 = s1[a][3 + f], x2 = s1[a][6 + f];
      s2[a][0][f] = x0;
      s2[a][1][f] = 0.5f * (x0 + x1 + x2);
      s2[a][2][f] = 0.5f * (x0 - x1 + x2);
      s2[a][3][f] = x2;
    }
#pragma unroll
  for (int a = 0; a < 4; ++a)
#pragma unroll
    for (int b = 0; b < 4; ++b) {
      float x0 = s2[a][b][0], x1 = s2[a][b][1], x2 = s2[a][b][2];
      size_t ab = (size_t)(a * 16 + b * 4) * 16384 + base2;
      U[ab + 0 * 16384] = f2bf(x0);
      U[ab + 1 * 16384] = f2bf(0.5f * (x0 + x1 + x2));
      U[ab + 2 * 16384] = f2bf(0.5f * (x0 - x1 + x2));
      U[ab + 3 * 16384] = f2bf(x2);
    }
}

// ---------------- K2: input transform, lane=ci ----------------
// Block: 512 thr = 8 waves; covers 32 tiles (2 td x 4 th x 4 tw) x 64 ci.
// Wave wv handles tiles wv*4..wv*4+3; lane = ci. Slab fp32 [64][601]
// (spatial 6x10x10 = 600, odd stride -> conflict-free lane-strided reads).
// Per tile: 64 ds_read_b32 -> streamed Bt^3 -> 64 global_store_short, each a
// full 128B line (64 lanes x 2B, ci-contiguous). Grid 256/img, XCD-chunked.
// Bt rows: r0=x0-x2, r1=x1+x2, r2=x2-x1, r3=x1-x3
__global__ __launch_bounds__(512) void vt_kernel(const float* __restrict__ x,
                                                 unsigned short* __restrict__ V, int n_base,
                                                 int nt_slice) {
  __shared__ __align__(16) float slab[64 * 601];  // 153,856 B

  const int tid = threadIdx.x;
  const int B = blockIdx.x;
  const int n_l = B >> 8;
  const int Bl = B & 255;
  // XCD-chunk swizzle: dispatch id -> work id so each XCD gets a spatially
  // contiguous 32-block chunk (halo lines shared within one L2).
  const int W = ((Bl & 7) << 5) | (Bl >> 3);
  const int btw = W & 3;
  const int bth = (W >> 2) & 3;
  const int btd = (W >> 4) & 7;
  const int cih = W >> 7;

  const int n = n_base + n_l;
  const int CI0 = cih * 64;
  const int d0 = 4 * btd - 1, h0 = 8 * bth - 1, w0 = 8 * btw - 1;
  const int tg_base = n_l * 4096 + (btd * 2) * 256 + (bth * 4) * 16 + (btw * 4);

  // ---- fill slab: 64 ci x 600 spatial, zero-padded at volume borders ----
  const float* xb = x + (size_t)(n * 128 + CI0) * 32768;
#pragma unroll 1
  for (int k = 0; k < 75; ++k) {
    int i = tid + k * 512;
    int ci = i / 600, s = i - ci * 600;
    int dd = s / 100, r = s - dd * 100;
    int hh = r / 10, ww = r - hh * 10;
    int dg = d0 + dd, hg = h0 + hh, wg = w0 + ww;
    float v = 0.0f;
    if ((unsigned)dg < 32u && (unsigned)hg < 32u && (unsigned)wg < 32u)
      v = xb[(size_t)ci * 32768 + (dg * 32 + hg) * 32 + wg];
    slab[ci * 601 + s] = v;
  }
  __syncthreads();

  // ---- transform: wave wv, lane = ci; 4 tiles per wave ----
  const int lane = tid & 63;
  const int wv = tid >> 6;
  const float* sl = slab + lane * 601;
  const size_t nt128 = (size_t)nt_slice * 128;

#pragma unroll 1
  for (int j = 0; j < 4; ++j) {
    int tt = wv * 4 + j;
    int ltd = tt >> 4, lth = (tt >> 2) & 3, ltw = tt & 3;
    const float* sp = sl + ((2 * ltd) * 10 + (2 * lth)) * 10 + (2 * ltw);

    float s1[4][16];  // [fd-row][fh*4+fw]
#pragma unroll
    for (int fh = 0; fh < 4; ++fh)
#pragma unroll
      for (int fw = 0; fw < 4; ++fw) {
        float x0 = sp[(0 * 10 + fh) * 10 + fw];
        float x1 = sp[(1 * 10 + fh) * 10 + fw];
        float x2 = sp[(2 * 10 + fh) * 10 + fw];
        float x3 = sp[(3 * 10 + fh) * 10 + fw];
        s1[0][fh * 4 + fw] = x0 - x2;
        s1[1][fh * 4 + fw] = x1 + x2;
        s1[2][fh * 4 + fw] = x2 - x1;
        s1[3][fh * 4 + fw] = x1 - x3;
      }

    int tg = tg_base + ltd * 256 + lth * 16 + ltw;
    unsigned short* vp = V + (size_t)tg * 128 + CI0 + lane;

#pragma unroll
    for (int a = 0; a < 4; ++a) {
      float s2[4][4];  // [b-row][fw]
#pragma unroll
      for (int fw = 0; fw < 4; ++fw) {
        float t0 = s1[a][0 + fw], t1 = s1[a][4 + fw], t2 = s1[a][8 + fw], t3 = s1[a][12 + fw];
        s2[0][fw] = t0 - t2;
        s2[1][fw] = t1 + t2;
        s2[2][fw] = t2 - t1;
        s2[3][fw] = t1 - t3;
      }
#pragma unroll
      for (int bb = 0; bb < 4; ++bb) {
        float x0 = s2[bb][0], x1 = s2[bb][1], x2 = s2[bb][2], x3 = s2[bb][3];
        size_t ab = (size_t)(a * 16 + bb * 4) * nt128;
        vp[ab + 0 * nt128] = f2bf(x0 - x2);
        vp[ab + 1 * nt128] = f2bf(x1 + x2);
        vp[ab + 2 * nt128] = f2bf(x2 - x1);
        vp[ab + 3 * nt128] = f2bf(x1 - x3);
      }
    }
  }
}

// ---------------- K3: batched GEMM + fused inverse transform ----------------
// Grid: img x 4 o-groups(32o) x 128 t-blocks(32t). Block 128 thr = 2 waves,
// each wave 16o x 32t. V staged in 4-deep LDS ring (8KB tiles) via
// global_load_lds (linear dest, inverse-swizzled source); U prefetched into
// rotating registers at the same depth so the per-wave vmcnt stream stays
// uniform: per iter 4 V-lds + 4 U loads -> steady-state s_waitcnt vmcnt(12)
// + raw s_barrier (never drain to 0 in the loop).
__global__ __launch_bounds__(128, 3) void wg_gemm(const unsigned short* __restrict__ U,
                                                  const unsigned short* __restrict__ V,
                                                  float* __restrict__ y, int n_base,
                                                  int nt_slice) {
  __shared__ __align__(16) unsigned short vbuf[4][32 * 128];  // 4 x 8 KB
  const int tid = threadIdx.x;
  const int lane = tid & 63;
  const int wid = tid >> 6;  // 0..1
  const int b = blockIdx.x;
  const int img = b >> 9;
  const int og = (b >> 7) & 3;
  const int tblk = b & 127;
  const int tb = img * 4096 + tblk * 32;  // slice-local tile base
  const int g = og * 2 + wid;             // o-16-group
  const int lo = lane & 15;
  const int hi = lane >> 4;

  const unsigned short* Ug = U + (size_t)g * 2048 + (size_t)lane * 8;

  const f32x4 zf = {0.f, 0.f, 0.f, 0.f};
  f32x4 Y[2][2][2][2];  // [f][k][l][m]
#pragma unroll
  for (int f = 0; f < 2; ++f)
#pragma unroll
    for (int k = 0; k < 2; ++k)
#pragma unroll
      for (int l = 0; l < 2; ++l)
#pragma unroll
        for (int m = 0; m < 2; ++m) Y[f][k][l][m] = zf;
  f32x4 P0[2], P1[2];
  short8 ua[2][4];

  auto stageV = [&](int i) {
    int a = i & 3, bc = i >> 2;
    int abc = a * 16 + bc;
    const char* src = (const char*)(V + ((size_t)abc * nt_slice + tb) * 128);
    char* dstb = (char*)&vbuf[i & 3][0];
#pragma unroll
    for (int it = 0; it < 4; ++it) {
      int L = (tid + it * 128) * 16;
      int t = L >> 8, bo = L & 255;
      int sb = bo ^ ((t & 7) << 4);  // inverse-swizzled global source
      __builtin_amdgcn_global_load_lds((gas_cvp)(src + t * 256 + sb), (las_vp)(dstb + L), 16, 0,
                                       0);
    }
  };
  auto loadU = [&](int i, short8* dst) {
    int a = i & 3, bc = i >> 2;
    int abc = a * 16 + bc;
    const unsigned short* up = Ug + (size_t)abc * 16384;
#pragma unroll
    for (int ks = 0; ks < 4; ++ks) dst[ks] = *(const short8*)(up + ks * 512);
  };

  // prologue: 2 tiles in flight
  stageV(0);
  loadU(0, ua[0]);
  stageV(1);
  loadU(1, ua[1]);

  for (int j4 = 0; j4 < 64; j4 += 4) {
    int bc = j4 >> 2;
#pragma unroll
    for (int p = 0; p < 4; ++p) {
      int i = j4 + p;
      if (i < 62) stageV(i + 2);
      if (i < 62)
        asm volatile("s_waitcnt vmcnt(12)" ::: "memory");
      else if (i == 62)
        asm volatile("s_waitcnt vmcnt(8)" ::: "memory");
      else
        asm volatile("s_waitcnt vmcnt(0)" ::: "memory");
      __builtin_amdgcn_s_barrier();
      const char* vb = (const char*)&vbuf[p][0];  // i & 3 == p
      f32x4 M[2];
#pragma unroll
      for (int ks = 0; ks < 4; ++ks) {
#pragma unroll
        for (int f = 0; f < 2; ++f) {
          int t = f * 16 + lo;
          int boff = (t * 256 + ks * 64 + hi * 16) ^ ((t & 7) << 4);
          short8 Bf = *(const short8*)(vb + boff);
          M[f] = __builtin_amdgcn_mfma_f32_16x16x32_bf16(ua[p & 1][ks], Bf,
                                                         (ks == 0) ? zf : M[f], 0, 0, 0);
        }
      }
      // At rows: [1,1,1,0], [0,1,-1,-1]; a == p
#pragma unroll
      for (int f = 0; f < 2; ++f) {
        if (p == 0) {
          P0[f] = M[f];
          P1[f] = zf;
        } else if (p == 1) {
          P0[f] += M[f];
          P1[f] = M[f];
        } else if (p == 2) {
          P0[f] += M[f];
          P1[f] -= M[f];
        } else {
          P1[f] -= M[f];
        }
      }
      if (i < 62) loadU(i + 2, ua[p & 1]);
    }
    int bq = bc >> 2, cq = bc & 3;
    float cl0 = (bq == 3) ? 0.f : 1.f;
    float cl1 = (bq == 0) ? 0.f : ((bq == 1) ? 1.f : -1.f);
    float cm0 = (cq == 3) ? 0.f : 1.f;
    float cm1 = (cq == 0) ? 0.f : ((cq == 1) ? 1.f : -1.f);
    float c00 = cl0 * cm0, c01 = cl0 * cm1, c10 = cl1 * cm0, c11 = cl1 * cm1;
#pragma unroll
    for (int f = 0; f < 2; ++f) {
      Y[f][0][0][0] += c00 * P0[f];
      Y[f][0][0][1] += c01 * P0[f];
      Y[f][0][1][0] += c10 * P0[f];
      Y[f][0][1][1] += c11 * P0[f];
      Y[f][1][0][0] += c00 * P1[f];
      Y[f][1][0][1] += c01 * P1[f];
      Y[f][1][1][0] += c10 * P1[f];
      Y[f][1][1][1] += c11 * P1[f];
    }
  }

  // write out: o = g*16 + hi*4 + q; t = tb + f*16 + lo
#pragma unroll
  for (int f = 0; f < 2; ++f) {
    int tg = tb + f * 16 + lo;
    int n = n_base + (tg >> 12);
    int rem = tg & 4095;
    int td = rem >> 8, th = (rem >> 4) & 15, tw = rem & 15;
#pragma unroll
    for (int q = 0; q < 4; ++q) {
      int o = g * 16 + hi * 4 + q;
      float* pb = y + (size_t)(n * 128 + o) * 32768 + 2 * tw;
#pragma unroll
      for (int k = 0; k < 2; ++k)
#pragma unroll
        for (int l = 0; l < 2; ++l) {
          float* p = pb + (2 * td + k) * 1024 + (2 * th + l) * 32;
          *(float2*)p = make_float2(Y[f][k][l][0][q], Y[f][k][l][1][q]);
        }
    }
  }
}

extern "C" void kernel_launch(void* const* d_in, const int* in_sizes, int n_in, void* d_out,
                              int out_size, void* d_ws, size_t ws_size, hipStream_t stream) {
  const float* x = (const float*)d_in[0];
  const float* w = (const float*)d_in[1];
  float* y = (float*)d_out;
  char* ws = (char*)d_ws;
  unsigned short* U = (unsigned short*)ws;
  unsigned short* V = (unsigned short*)(ws + (4ull << 20));
  const size_t per_img = 64ull * 4096 * 128 * 2;  // 64 MiB of V per image
  int n_s = 1;
  if (ws_size >= (4ull << 20) + 4 * per_img)
    n_s = 4;
  else if (ws_size >= (4ull << 20) + 2 * per_img)
    n_s = 2;

  wt_kernel<<<64, 256, 0, stream>>>(w, U);
  for (int nb = 0; nb < 4; nb += n_s) {
    int nt_slice = 4096 * n_s;
    vt_kernel<<<dim3(256 * n_s), 512, 0, stream>>>(x, V, nb, nt_slice);
    wg_gemm<<<dim3(512 * n_s), 128, 0, stream>>>(U, V, y, nb, nt_slice);
  }
}

// Round 5
// 331.641 us; speedup vs baseline: 1.4607x; 1.4234x over previous
//
#include <hip/hip_runtime.h>

// Winograd F(2x2x2, 3x3x3) conv: N=4, Ci=Co=128, D=H=W=32, T=16 tiles/dim.
// K1: weight transform into MFMA-fragment-ordered U2.
// K2: input transform, lane=ci: fp32 slab [64ci][601] (conflict-free), batched
//     register-staged fill (15 loads in flight), stores V as full 128B lines;
//     V layout [abc][cih][t][64ci] so both halves of each 256B HBM line come
//     from the same block (kills 2x write amplification).
// K3: 64 batched GEMMs with fused inverse transform; counted-vmcnt pipeline
//     (depth 2), V staged via global_load_lds ring, U prefetched to regs.

typedef short short8 __attribute__((ext_vector_type(8)));
typedef float f32x4 __attribute__((ext_vector_type(4)));

typedef __attribute__((address_space(1))) const void* gas_cvp;
typedef __attribute__((address_space(3))) void* las_vp;

__device__ __forceinline__ unsigned short f2bf(float f) {
  unsigned u = __float_as_uint(f);
  u += 0x7FFFu + ((u >> 16) & 1u);
  return (unsigned short)(u >> 16);
}

// ---------------- K1: weight transform ----------------
// U2 element for (abc, o, ci) lives at
//   abc*16384 + ((g*4 + ks)*64 + hi*16 + lo)*8 + j
// with g=o>>4, lo=o&15, ks=ci>>5, hi=(ci>>3)&3, j=ci&7 -- so a wave's A-frag
// load (lane = hi*16+lo, 16B x 4ks) is fully coalesced (1KB/instr).
__global__ void wt_kernel(const float* __restrict__ w, unsigned short* __restrict__ U) {
  int tid = blockIdx.x * 256 + threadIdx.x;  // 16384 threads
  int ci = tid & 127, o = tid >> 7;
  int g = o >> 4, lo = o & 15, ks = ci >> 5, hi = (ci >> 3) & 3, jj = ci & 7;
  int base2 = ((g * 4 + ks) * 64 + hi * 16 + lo) * 8 + jj;
  const float* wp = w + (size_t)(o * 128 + ci) * 27;
  float in[27];
#pragma unroll
  for (int j = 0; j < 27; ++j) in[j] = wp[j];
  float s1[4][9];
#pragma unroll
  for (int ef = 0; ef < 9; ++ef) {
    float x0 = in[ef], x1 = in[9 + ef], x2 = in[18 + ef];
    s1[0][ef] = x0;
    s1[1][ef] = 0.5f * (x0 + x1 + x2);
    s1[2][ef] = 0.5f * (x0 - x1 + x2);
    s1[3][ef] = x2;
  }
  float s2[4][4][3];
#pragma unroll
  for (int a = 0; a < 4; ++a)
#pragma unroll
    for (int f = 0; f < 3; ++f) {
      float x0 = s1[a][f], x1 = s1[a][3 + f], x2 = s1[a][6 + f];
      s2[a][0][f] = x0;
      s2[a][1][f] = 0.5f * (x0 + x1 + x2);
      s2[a][2][f] = 0.5f * (x0 - x1 + x2);
      s2[a][3][f] = x2;
    }
#pragma unroll
  for (int a = 0; a < 4; ++a)
#pragma unroll
    for (int b = 0; b < 4; ++b) {
      float x0 = s2[a][b][0], x1 = s2[a][b][1], x2 = s2[a][b][2];
      size_t ab = (size_t)(a * 16 + b * 4) * 16384 + base2;
      U[ab + 0 * 16384] = f2bf(x0);
      U[ab + 1 * 16384] = f2bf(0.5f * (x0 + x1 + x2));
      U[ab + 2 * 16384] = f2bf(0.5f * (x0 - x1 + x2));
      U[ab + 3 * 16384] = f2bf(x2);
    }
}

// ---------------- K2: input transform, lane=ci ----------------
// Block: 512 thr = 8 waves; covers 32 tiles (2 td x 4 th x 4 tw) x 64 ci.
// Wave wv handles 4 consecutive-tw tiles; lane = ci. Slab fp32 [64][601].
// Fill is register-batched (15 loads in flight). V[abc][cih][t][64ci]:
// per-row 128B wave store; tg/tg+1 (same 256B line) written by the same wave.
// Bt rows: r0=x0-x2, r1=x1+x2, r2=x2-x1, r3=x1-x3
__global__ __launch_bounds__(512) void vt_kernel(const float* __restrict__ x,
                                                 unsigned short* __restrict__ V, int n_base,
                                                 int nt_slice) {
  __shared__ __align__(16) float slab[64 * 601];  // 153,856 B

  const int tid = threadIdx.x;
  const int B = blockIdx.x;
  const int n_l = B >> 8;
  const int Bl = B & 255;
  // XCD-chunk swizzle: each XCD gets a spatially contiguous 32-block chunk.
  const int W = ((Bl & 7) << 5) | (Bl >> 3);
  const int btw = W & 3;
  const int bth = (W >> 2) & 3;
  const int btd = (W >> 4) & 7;
  const int cihb = W >> 7;

  const int n = n_base + n_l;
  const int CI0 = cihb * 64;
  const int d0 = 4 * btd - 1, h0 = 8 * bth - 1, w0 = 8 * btw - 1;
  const int tg_base = n_l * 4096 + (btd * 2) * 256 + (bth * 4) * 16 + (btw * 4);
  const int NT = nt_slice;

  // ---- fill slab: 64 ci x 600 spatial, zero-padded; 15 loads in flight ----
  const float* xb = x + (size_t)(n * 128 + CI0) * 32768;
#pragma unroll 1
  for (int kb = 0; kb < 75; kb += 15) {
    float r[15];
    int off[15];
#pragma unroll
    for (int j = 0; j < 15; ++j) {
      int i = tid + (kb + j) * 512;
      int ci = i / 600, s = i - ci * 600;
      int dd = s / 100, rr = s - dd * 100;
      int hh = rr / 10, ww = rr - hh * 10;
      int dg = d0 + dd, hg = h0 + hh, wg = w0 + ww;
      bool ok = ((unsigned)dg < 32u) && ((unsigned)hg < 32u) && ((unsigned)wg < 32u);
      float v = 0.0f;
      if (ok) v = xb[(size_t)ci * 32768 + (dg * 32 + hg) * 32 + wg];
      r[j] = v;
      off[j] = ci * 601 + s;
    }
#pragma unroll
    for (int j = 0; j < 15; ++j) slab[off[j]] = r[j];
  }
  __syncthreads();

  // ---- transform: wave wv, lane = ci; 4 consecutive-tw tiles per wave ----
  const int lane = tid & 63;
  const int wv = tid >> 6;
  const float* sl = slab + lane * 601;
  const size_t strA = (size_t)NT * 128;  // per-abc element stride

#pragma unroll 1
  for (int j = 0; j < 4; ++j) {
    int tt = wv * 4 + j;
    int ltd = tt >> 4, lth = (tt >> 2) & 3, ltw = tt & 3;
    const float* sp = sl + ((2 * ltd) * 10 + (2 * lth)) * 10 + (2 * ltw);

    float s1[4][16];  // [fd-row][fh*4+fw]
#pragma unroll
    for (int fh = 0; fh < 4; ++fh)
#pragma unroll
      for (int fw = 0; fw < 4; ++fw) {
        float x0 = sp[(0 * 10 + fh) * 10 + fw];
        float x1 = sp[(1 * 10 + fh) * 10 + fw];
        float x2 = sp[(2 * 10 + fh) * 10 + fw];
        float x3 = sp[(3 * 10 + fh) * 10 + fw];
        s1[0][fh * 4 + fw] = x0 - x2;
        s1[1][fh * 4 + fw] = x1 + x2;
        s1[2][fh * 4 + fw] = x2 - x1;
        s1[3][fh * 4 + fw] = x1 - x3;
      }

    int tg = tg_base + ltd * 256 + lth * 16 + ltw;
    unsigned short* vp = V + ((size_t)cihb * NT + tg) * 64 + lane;

#pragma unroll
    for (int a = 0; a < 4; ++a) {
      float s2[4][4];  // [b-row][fw]
#pragma unroll
      for (int fw = 0; fw < 4; ++fw) {
        float t0 = s1[a][0 + fw], t1 = s1[a][4 + fw], t2 = s1[a][8 + fw], t3 = s1[a][12 + fw];
        s2[0][fw] = t0 - t2;
        s2[1][fw] = t1 + t2;
        s2[2][fw] = t2 - t1;
        s2[3][fw] = t1 - t3;
      }
#pragma unroll
      for (int bb = 0; bb < 4; ++bb) {
        float x0 = s2[bb][0], x1 = s2[bb][1], x2 = s2[bb][2], x3 = s2[bb][3];
        size_t ab = (size_t)(a * 16 + bb * 4) * strA;
        vp[ab + 0 * strA] = f2bf(x0 - x2);
        vp[ab + 1 * strA] = f2bf(x1 + x2);
        vp[ab + 2 * strA] = f2bf(x2 - x1);
        vp[ab + 3 * strA] = f2bf(x1 - x3);
      }
    }
  }
}

// ---------------- K3: batched GEMM + fused inverse transform ----------------
// Grid: img x 4 o-groups(32o) x 128 t-blocks(32t). Block 128 thr = 2 waves,
// each wave 16o x 32t. V[abc][cih][t][64ci]: per abc two contiguous 4KB
// regions staged into a 4-deep LDS ring (8KB tiles) via global_load_lds
// (linear dest, inverse-swizzled source within each 128B row); U prefetched
// into rotating regs at the same depth: per iter 4 V-lds + 4 U loads ->
// steady-state s_waitcnt vmcnt(12) + raw s_barrier (never 0 in the loop).
__global__ __launch_bounds__(128, 3) void wg_gemm(const unsigned short* __restrict__ U,
                                                  const unsigned short* __restrict__ V,
                                                  float* __restrict__ y, int n_base,
                                                  int nt_slice) {
  __shared__ __align__(16) unsigned short vbuf[4][32 * 128];  // 4 x 8 KB
  const int tid = threadIdx.x;
  const int lane = tid & 63;
  const int wid = tid >> 6;  // 0..1
  const int b = blockIdx.x;
  const int img = b >> 9;
  const int og = (b >> 7) & 3;
  const int tblk = b & 127;
  const int tb = img * 4096 + tblk * 32;  // slice-local tile base
  const int g = og * 2 + wid;             // o-16-group
  const int lo = lane & 15;
  const int hi = lane >> 4;
  const int NT = nt_slice;

  const unsigned short* Ug = U + (size_t)g * 2048 + (size_t)lane * 8;

  const f32x4 zf = {0.f, 0.f, 0.f, 0.f};
  f32x4 Y[2][2][2][2];  // [f][k][l][m]
#pragma unroll
  for (int f = 0; f < 2; ++f)
#pragma unroll
    for (int k = 0; k < 2; ++k)
#pragma unroll
      for (int l = 0; l < 2; ++l)
#pragma unroll
        for (int m = 0; m < 2; ++m) Y[f][k][l][m] = zf;
  f32x4 P0[2], P1[2];
  short8 ua[2][4];

  auto stageV = [&](int i) {
    int a = i & 3, bc = i >> 2;
    int abc = a * 16 + bc;
    const char* src0 = (const char*)V + ((size_t)abc * 2 * NT + tb) * 128;
    char* dstb = (char*)&vbuf[i & 3][0];
#pragma unroll
    for (int it = 0; it < 4; ++it) {
      int L = tid * 16 + it * 2048;
      int cihr = L >> 12;
      int tl = (L >> 7) & 31;
      int bo = L & 127;
      int sb = bo ^ ((tl & 7) << 4);  // inverse-swizzled source within row
      __builtin_amdgcn_global_load_lds((gas_cvp)(src0 + (size_t)cihr * NT * 128 + tl * 128 + sb),
                                       (las_vp)(dstb + L), 16, 0, 0);
    }
  };
  auto loadU = [&](int i, short8* dst) {
    int a = i & 3, bc = i >> 2;
    int abc = a * 16 + bc;
    const unsigned short* up = Ug + (size_t)abc * 16384;
#pragma unroll
    for (int ks = 0; ks < 4; ++ks) dst[ks] = *(const short8*)(up + ks * 512);
  };

  // prologue: 2 tiles in flight
  stageV(0);
  loadU(0, ua[0]);
  stageV(1);
  loadU(1, ua[1]);

  for (int j4 = 0; j4 < 64; j4 += 4) {
    int bc = j4 >> 2;
#pragma unroll
    for (int p = 0; p < 4; ++p) {
      int i = j4 + p;
      if (i < 62) stageV(i + 2);
      if (i < 62)
        asm volatile("s_waitcnt vmcnt(12)" ::: "memory");
      else if (i == 62)
        asm volatile("s_waitcnt vmcnt(8)" ::: "memory");
      else
        asm volatile("s_waitcnt vmcnt(0)" ::: "memory");
      __builtin_amdgcn_s_barrier();
      const char* vb = (const char*)&vbuf[p][0];  // i & 3 == p
      f32x4 M[2];
#pragma unroll
      for (int ks = 0; ks < 4; ++ks) {
#pragma unroll
        for (int f = 0; f < 2; ++f) {
          int t = f * 16 + lo;
          int bo = (ks & 1) * 64 + hi * 16;
          int boff = (ks >> 1) * 4096 + t * 128 + (bo ^ ((t & 7) << 4));
          short8 Bf = *(const short8*)(vb + boff);
          M[f] = __builtin_amdgcn_mfma_f32_16x16x32_bf16(ua[p & 1][ks], Bf,
                                                         (ks == 0) ? zf : M[f], 0, 0, 0);
        }
      }
      // At rows: [1,1,1,0], [0,1,-1,-1]; a == p
#pragma unroll
      for (int f = 0; f < 2; ++f) {
        if (p == 0) {
          P0[f] = M[f];
          P1[f] = zf;
        } else if (p == 1) {
          P0[f] += M[f];
          P1[f] = M[f];
        } else if (p == 2) {
          P0[f] += M[f];
          P1[f] -= M[f];
        } else {
          P1[f] -= M[f];
        }
      }
      if (i < 62) loadU(i + 2, ua[p & 1]);
    }
    int bq = bc >> 2, cq = bc & 3;
    float cl0 = (bq == 3) ? 0.f : 1.f;
    float cl1 = (bq == 0) ? 0.f : ((bq == 1) ? 1.f : -1.f);
    float cm0 = (cq == 3) ? 0.f : 1.f;
    float cm1 = (cq == 0) ? 0.f : ((cq == 1) ? 1.f : -1.f);
    float c00 = cl0 * cm0, c01 = cl0 * cm1, c10 = cl1 * cm0, c11 = cl1 * cm1;
#pragma unroll
    for (int f = 0; f < 2; ++f) {
      Y[f][0][0][0] += c00 * P0[f];
      Y[f][0][0][1] += c01 * P0[f];
      Y[f][0][1][0] += c10 * P0[f];
      Y[f][0][1][1] += c11 * P0[f];
      Y[f][1][0][0] += c00 * P1[f];
      Y[f][1][0][1] += c01 * P1[f];
      Y[f][1][1][0] += c10 * P1[f];
      Y[f][1][1][1] += c11 * P1[f];
    }
  }

  // write out: o = g*16 + hi*4 + q; t = tb + f*16 + lo
#pragma unroll
  for (int f = 0; f < 2; ++f) {
    int tg = tb + f * 16 + lo;
    int n = n_base + (tg >> 12);
    int rem = tg & 4095;
    int td = rem >> 8, th = (rem >> 4) & 15, tw = rem & 15;
#pragma unroll
    for (int q = 0; q < 4; ++q) {
      int o = g * 16 + hi * 4 + q;
      float* pb = y + (size_t)(n * 128 + o) * 32768 + 2 * tw;
#pragma unroll
      for (int k = 0; k < 2; ++k)
#pragma unroll
        for (int l = 0; l < 2; ++l) {
          float* p = pb + (2 * td + k) * 1024 + (2 * th + l) * 32;
          *(float2*)p = make_float2(Y[f][k][l][0][q], Y[f][k][l][1][q]);
        }
    }
  }
}

extern "C" void kernel_launch(void* const* d_in, const int* in_sizes, int n_in, void* d_out,
                              int out_size, void* d_ws, size_t ws_size, hipStream_t stream) {
  const float* x = (const float*)d_in[0];
  const float* w = (const float*)d_in[1];
  float* y = (float*)d_out;
  char* ws = (char*)d_ws;
  unsigned short* U = (unsigned short*)ws;
  unsigned short* V = (unsigned short*)(ws + (4ull << 20));
  const size_t per_img = 64ull * 4096 * 128 * 2;  // 64 MiB of V per image
  int n_s = 1;
  if (ws_size >= (4ull << 20) + 4 * per_img)
    n_s = 4;
  else if (ws_size >= (4ull << 20) + 2 * per_img)
    n_s = 2;

  wt_kernel<<<64, 256, 0, stream>>>(w, U);
  for (int nb = 0; nb < 4; nb += n_s) {
    int nt_slice = 4096 * n_s;
    vt_kernel<<<dim3(256 * n_s), 512, 0, stream>>>(x, V, nb, nt_slice);
    wg_gemm<<<dim3(512 * n_s), 128, 0, stream>>>(U, V, y, nb, nt_slice);
  }
}

// Round 6
// 289.533 us; speedup vs baseline: 1.6731x; 1.1454x over previous
//
#include <hip/hip_runtime.h>

// Winograd F(2x2x2, 3x3x3) conv: N=4, Ci=Co=128, D=H=W=32, T=16 tiles/dim.
// K1: weight transform into MFMA-fragment-ordered U2.
// K2: input transform, lane=ci, fp32 slab [64ci][601]; V is TILE-MAJOR:
//     V[cih][t][abc(64)][ci(64)] so each wave's 256 stores for one tile fill
//     one contiguous 8KB span (full 256B lines, 1x write amp, seq DRAM).
// K3: 64 batched GEMMs with fused inverse transform; counted-vmcnt pipeline
//     (depth 2); per block V is two contiguous 256KB streams; U prefetched
//     into rotating regs. LDS image identical to prior (verified) round.

typedef short short8 __attribute__((ext_vector_type(8)));
typedef float f32x4 __attribute__((ext_vector_type(4)));

typedef __attribute__((address_space(1))) const void* gas_cvp;
typedef __attribute__((address_space(3))) void* las_vp;

__device__ __forceinline__ unsigned short f2bf(float f) {
  unsigned u = __float_as_uint(f);
  u += 0x7FFFu + ((u >> 16) & 1u);
  return (unsigned short)(u >> 16);
}

// ---------------- K1: weight transform ----------------
// U2 element for (abc, o, ci) lives at
//   abc*16384 + ((g*4 + ks)*64 + hi*16 + lo)*8 + j
// with g=o>>4, lo=o&15, ks=ci>>5, hi=(ci>>3)&3, j=ci&7 -- so a wave's A-frag
// load (lane = hi*16+lo, 16B x 4ks) is fully coalesced (1KB/instr).
__global__ void wt_kernel(const float* __restrict__ w, unsigned short* __restrict__ U) {
  int tid = blockIdx.x * 256 + threadIdx.x;  // 16384 threads
  int ci = tid & 127, o = tid >> 7;
  int g = o >> 4, lo = o & 15, ks = ci >> 5, hi = (ci >> 3) & 3, jj = ci & 7;
  int base2 = ((g * 4 + ks) * 64 + hi * 16 + lo) * 8 + jj;
  const float* wp = w + (size_t)(o * 128 + ci) * 27;
  float in[27];
#pragma unroll
  for (int j = 0; j < 27; ++j) in[j] = wp[j];
  float s1[4][9];
#pragma unroll
  for (int ef = 0; ef < 9; ++ef) {
    float x0 = in[ef], x1 = in[9 + ef], x2 = in[18 + ef];
    s1[0][ef] = x0;
    s1[1][ef] = 0.5f * (x0 + x1 + x2);
    s1[2][ef] = 0.5f * (x0 - x1 + x2);
    s1[3][ef] = x2;
  }
  float s2[4][4][3];
#pragma unroll
  for (int a = 0; a < 4; ++a)
#pragma unroll
    for (int f = 0; f < 3; ++f) {
      float x0 = s1[a][f], x1 = s1[a][3 + f], x2 = s1[a][6 + f];
      s2[a][0][f] = x0;
      s2[a][1][f] = 0.5f * (x0 + x1 + x2);
      s2[a][2][f] = 0.5f * (x0 - x1 + x2);
      s2[a][3][f] = x2;
    }
#pragma unroll
  for (int a = 0; a < 4; ++a)
#pragma unroll
    for (int b = 0; b < 4; ++b) {
      float x0 = s2[a][b][0], x1 = s2[a][b][1], x2 = s2[a][b][2];
      size_t ab = (size_t)(a * 16 + b * 4) * 16384 + base2;
      U[ab + 0 * 16384] = f2bf(x0);
      U[ab + 1 * 16384] = f2bf(0.5f * (x0 + x1 + x2));
      U[ab + 2 * 16384] = f2bf(0.5f * (x0 - x1 + x2));
      U[ab + 3 * 16384] = f2bf(x2);
    }
}

// ---------------- K2: input transform, lane=ci, tile-major V ----------------
// Block: 512 thr = 8 waves; covers 32 tiles (2 td x 4 th x 4 tw) x 64 ci.
// Wave wv handles 4 consecutive-tw tiles; lane = ci. Slab fp32 [64][601].
// Fill register-batched (15 loads in flight). Store: per tile, 64 abc rows of
// 128B inside ONE contiguous 8KB span: V[(cih*NT+t)*4096 + abc*64 + ci].
// Bt rows: r0=x0-x2, r1=x1+x2, r2=x2-x1, r3=x1-x3
__global__ __launch_bounds__(512) void vt_kernel(const float* __restrict__ x,
                                                 unsigned short* __restrict__ V, int n_base,
                                                 int nt_slice) {
  __shared__ __align__(16) float slab[64 * 601];  // 153,856 B

  const int tid = threadIdx.x;
  const int B = blockIdx.x;
  const int n_l = B >> 8;
  const int Bl = B & 255;
  // XCD-chunk swizzle: each XCD gets a spatially contiguous 32-block chunk.
  const int W = ((Bl & 7) << 5) | (Bl >> 3);
  const int btw = W & 3;
  const int bth = (W >> 2) & 3;
  const int btd = (W >> 4) & 7;
  const int cihb = W >> 7;

  const int n = n_base + n_l;
  const int CI0 = cihb * 64;
  const int d0 = 4 * btd - 1, h0 = 8 * bth - 1, w0 = 8 * btw - 1;
  const int tg_base = n_l * 4096 + (btd * 2) * 256 + (bth * 4) * 16 + (btw * 4);
  const int NT = nt_slice;

  // ---- fill slab: 64 ci x 600 spatial, zero-padded; 15 loads in flight ----
  const float* xb = x + (size_t)(n * 128 + CI0) * 32768;
#pragma unroll 1
  for (int kb = 0; kb < 75; kb += 15) {
    float r[15];
    int off[15];
#pragma unroll
    for (int j = 0; j < 15; ++j) {
      int i = tid + (kb + j) * 512;
      int ci = i / 600, s = i - ci * 600;
      int dd = s / 100, rr = s - dd * 100;
      int hh = rr / 10, ww = rr - hh * 10;
      int dg = d0 + dd, hg = h0 + hh, wg = w0 + ww;
      bool ok = ((unsigned)dg < 32u) && ((unsigned)hg < 32u) && ((unsigned)wg < 32u);
      float v = 0.0f;
      if (ok) v = xb[(size_t)ci * 32768 + (dg * 32 + hg) * 32 + wg];
      r[j] = v;
      off[j] = ci * 601 + s;
    }
#pragma unroll
    for (int j = 0; j < 15; ++j) slab[off[j]] = r[j];
  }
  __syncthreads();

  // ---- transform: wave wv, lane = ci; 4 consecutive-tw tiles per wave ----
  const int lane = tid & 63;
  const int wv = tid >> 6;
  const float* sl = slab + lane * 601;

#pragma unroll 1
  for (int j = 0; j < 4; ++j) {
    int tt = wv * 4 + j;
    int ltd = tt >> 4, lth = (tt >> 2) & 3, ltw = tt & 3;
    const float* sp = sl + ((2 * ltd) * 10 + (2 * lth)) * 10 + (2 * ltw);

    float s1[4][16];  // [fd-row][fh*4+fw]
#pragma unroll
    for (int fh = 0; fh < 4; ++fh)
#pragma unroll
      for (int fw = 0; fw < 4; ++fw) {
        float x0 = sp[(0 * 10 + fh) * 10 + fw];
        float x1 = sp[(1 * 10 + fh) * 10 + fw];
        float x2 = sp[(2 * 10 + fh) * 10 + fw];
        float x3 = sp[(3 * 10 + fh) * 10 + fw];
        s1[0][fh * 4 + fw] = x0 - x2;
        s1[1][fh * 4 + fw] = x1 + x2;
        s1[2][fh * 4 + fw] = x2 - x1;
        s1[3][fh * 4 + fw] = x1 - x3;
      }

    int tg = tg_base + ltd * 256 + lth * 16 + ltw;
    // tile-major: 8KB span for this (cih, t)
    unsigned short* vp = V + ((size_t)(cihb * NT + tg) << 12) + lane;

#pragma unroll
    for (int a = 0; a < 4; ++a) {
      float s2[4][4];  // [b-row][fw]
#pragma unroll
      for (int fw = 0; fw < 4; ++fw) {
        float t0 = s1[a][0 + fw], t1 = s1[a][4 + fw], t2 = s1[a][8 + fw], t3 = s1[a][12 + fw];
        s2[0][fw] = t0 - t2;
        s2[1][fw] = t1 + t2;
        s2[2][fw] = t2 - t1;
        s2[3][fw] = t1 - t3;
      }
#pragma unroll
      for (int bb = 0; bb < 4; ++bb) {
        float x0 = s2[bb][0], x1 = s2[bb][1], x2 = s2[bb][2], x3 = s2[bb][3];
        int ab = (a * 16 + bb * 4) * 64;  // abc*64 element offset
        vp[ab + 0 * 64] = f2bf(x0 - x2);
        vp[ab + 1 * 64] = f2bf(x1 + x2);
        vp[ab + 2 * 64] = f2bf(x2 - x1);
        vp[ab + 3 * 64] = f2bf(x1 - x3);
      }
    }
  }
}

// ---------------- K3: batched GEMM + fused inverse transform ----------------
// Grid: img x 4 o-groups(32o) x 128 t-blocks(32t). Block 128 thr = 2 waves,
// each wave 16o x 32t. V[cih][t][abc][ci]: block's V = two contiguous 256KB
// windows; per abc, 32 rows of 128B at stride 8KB staged into a 4-deep LDS
// ring (linear dest, inverse-swizzled source within each row); U prefetched
// into rotating regs: per iter 4 V-lds + 4 U loads -> steady-state
// s_waitcnt vmcnt(12) + raw s_barrier (never 0 in the loop).
__global__ __launch_bounds__(128, 3) void wg_gemm(const unsigned short* __restrict__ U,
                                                  const unsigned short* __restrict__ V,
                                                  float* __restrict__ y, int n_base,
                                                  int nt_slice) {
  __shared__ __align__(16) unsigned short vbuf[4][32 * 128];  // 4 x 8 KB
  const int tid = threadIdx.x;
  const int lane = tid & 63;
  const int wid = tid >> 6;  // 0..1
  const int b = blockIdx.x;
  const int img = b >> 9;
  const int og = (b >> 7) & 3;
  const int tblk = b & 127;
  const int tb = img * 4096 + tblk * 32;  // slice-local tile base
  const int g = og * 2 + wid;             // o-16-group
  const int lo = lane & 15;
  const int hi = lane >> 4;
  const int NT = nt_slice;

  const unsigned short* Ug = U + (size_t)g * 2048 + (size_t)lane * 8;

  const f32x4 zf = {0.f, 0.f, 0.f, 0.f};
  f32x4 Y[2][2][2][2];  // [f][k][l][m]
#pragma unroll
  for (int f = 0; f < 2; ++f)
#pragma unroll
    for (int k = 0; k < 2; ++k)
#pragma unroll
      for (int l = 0; l < 2; ++l)
#pragma unroll
        for (int m = 0; m < 2; ++m) Y[f][k][l][m] = zf;
  f32x4 P0[2], P1[2];
  short8 ua[2][4];

  // base of this block's V window: tile tb, cih 0, abc 0
  const char* Vwin = (const char*)V + ((size_t)tb << 13);
  const size_t cihStride = (size_t)NT << 13;  // cih step in bytes

  auto stageV = [&](int i) {
    int a = i & 3, bc = i >> 2;
    int abc = a * 16 + bc;
    const char* src0 = Vwin + abc * 128;
    char* dstb = (char*)&vbuf[i & 3][0];
#pragma unroll
    for (int it = 0; it < 4; ++it) {
      int L = tid * 16 + it * 2048;
      int cihr = L >> 12;
      int tl = (L >> 7) & 31;
      int bo = L & 127;
      int sb = bo ^ ((tl & 7) << 4);  // inverse-swizzled source within row
      __builtin_amdgcn_global_load_lds(
          (gas_cvp)(src0 + (size_t)cihr * cihStride + (size_t)tl * 8192 + sb),
          (las_vp)(dstb + L), 16, 0, 0);
    }
  };
  auto loadU = [&](int i, short8* dst) {
    int a = i & 3, bc = i >> 2;
    int abc = a * 16 + bc;
    const unsigned short* up = Ug + (size_t)abc * 16384;
#pragma unroll
    for (int ks = 0; ks < 4; ++ks) dst[ks] = *(const short8*)(up + ks * 512);
  };

  // prologue: 2 tiles in flight
  stageV(0);
  loadU(0, ua[0]);
  stageV(1);
  loadU(1, ua[1]);

  for (int j4 = 0; j4 < 64; j4 += 4) {
    int bc = j4 >> 2;
#pragma unroll
    for (int p = 0; p < 4; ++p) {
      int i = j4 + p;
      if (i < 62) stageV(i + 2);
      if (i < 62)
        asm volatile("s_waitcnt vmcnt(12)" ::: "memory");
      else if (i == 62)
        asm volatile("s_waitcnt vmcnt(8)" ::: "memory");
      else
        asm volatile("s_waitcnt vmcnt(0)" ::: "memory");
      __builtin_amdgcn_s_barrier();
      const char* vb = (const char*)&vbuf[p][0];  // i & 3 == p
      f32x4 M[2];
#pragma unroll
      for (int ks = 0; ks < 4; ++ks) {
#pragma unroll
        for (int f = 0; f < 2; ++f) {
          int t = f * 16 + lo;
          int bo = (ks & 1) * 64 + hi * 16;
          int boff = (ks >> 1) * 4096 + t * 128 + (bo ^ ((t & 7) << 4));
          short8 Bf = *(const short8*)(vb + boff);
          M[f] = __builtin_amdgcn_mfma_f32_16x16x32_bf16(ua[p & 1][ks], Bf,
                                                         (ks == 0) ? zf : M[f], 0, 0, 0);
        }
      }
      // At rows: [1,1,1,0], [0,1,-1,-1]; a == p
#pragma unroll
      for (int f = 0; f < 2; ++f) {
        if (p == 0) {
          P0[f] = M[f];
          P1[f] = zf;
        } else if (p == 1) {
          P0[f] += M[f];
          P1[f] = M[f];
        } else if (p == 2) {
          P0[f] += M[f];
          P1[f] -= M[f];
        } else {
          P1[f] -= M[f];
        }
      }
      if (i < 62) loadU(i + 2, ua[p & 1]);
    }
    int bq = bc >> 2, cq = bc & 3;
    float cl0 = (bq == 3) ? 0.f : 1.f;
    float cl1 = (bq == 0) ? 0.f : ((bq == 1) ? 1.f : -1.f);
    float cm0 = (cq == 3) ? 0.f : 1.f;
    float cm1 = (cq == 0) ? 0.f : ((cq == 1) ? 1.f : -1.f);
    float c00 = cl0 * cm0, c01 = cl0 * cm1, c10 = cl1 * cm0, c11 = cl1 * cm1;
#pragma unroll
    for (int f = 0; f < 2; ++f) {
      Y[f][0][0][0] += c00 * P0[f];
      Y[f][0][0][1] += c01 * P0[f];
      Y[f][0][1][0] += c10 * P0[f];
      Y[f][0][1][1] += c11 * P0[f];
      Y[f][1][0][0] += c00 * P1[f];
      Y[f][1][0][1] += c01 * P1[f];
      Y[f][1][1][0] += c10 * P1[f];
      Y[f][1][1][1] += c11 * P1[f];
    }
  }

  // write out: o = g*16 + hi*4 + q; t = tb + f*16 + lo
#pragma unroll
  for (int f = 0; f < 2; ++f) {
    int tg = tb + f * 16 + lo;
    int n = n_base + (tg >> 12);
    int rem = tg & 4095;
    int td = rem >> 8, th = (rem >> 4) & 15, tw = rem & 15;
#pragma unroll
    for (int q = 0; q < 4; ++q) {
      int o = g * 16 + hi * 4 + q;
      float* pb = y + (size_t)(n * 128 + o) * 32768 + 2 * tw;
#pragma unroll
      for (int k = 0; k < 2; ++k)
#pragma unroll
        for (int l = 0; l < 2; ++l) {
          float* p = pb + (2 * td + k) * 1024 + (2 * th + l) * 32;
          *(float2*)p = make_float2(Y[f][k][l][0][q], Y[f][k][l][1][q]);
        }
    }
  }
}

extern "C" void kernel_launch(void* const* d_in, const int* in_sizes, int n_in, void* d_out,
                              int out_size, void* d_ws, size_t ws_size, hipStream_t stream) {
  const float* x = (const float*)d_in[0];
  const float* w = (const float*)d_in[1];
  float* y = (float*)d_out;
  char* ws = (char*)d_ws;
  unsigned short* U = (unsigned short*)ws;
  unsigned short* V = (unsigned short*)(ws + (4ull << 20));
  const size_t per_img = 64ull * 4096 * 128 * 2;  // 64 MiB of V per image
  int n_s = 1;
  if (ws_size >= (4ull << 20) + 4 * per_img)
    n_s = 4;
  else if (ws_size >= (4ull << 20) + 2 * per_img)
    n_s = 2;

  wt_kernel<<<64, 256, 0, stream>>>(w, U);
  for (int nb = 0; nb < 4; nb += n_s) {
    int nt_slice = 4096 * n_s;
    vt_kernel<<<dim3(256 * n_s), 512, 0, stream>>>(x, V, nb, nt_slice);
    wg_gemm<<<dim3(512 * n_s), 128, 0, stream>>>(U, V, y, nb, nt_slice);
  }
}